// Round 8
// baseline (229.888 us; speedup 1.0000x reference)
//
#include <hip/hip_runtime.h>
#include <cstdint>
#include <cstddef>

// ---------------------------------------------------------------------------
// SOMFNN forward, 4 dispatches:
//   1. f2b_all   : convert x/W0/W1 to bf16, SENx row norms, colsum partials
//                  (per-block private rows, no atomics), zero accumulators
//   2. stau0     : 8 blocks, atomic partial sums + last-block finisher
//   3. gemm L0   : fused Gram(dens,S,e,diag)+sigmoid(hb,SENh,colsumH); the
//                  LAST block (done-counter) runs stau1 + decide0 + lamb0
//   4. gemm L1   : fused Gram+sigmoid(out); last block runs decide1 + lamb1
// Semantics (exact vs reference): stau=base/2 scalar (SENc==cn2); prototypes
// never updated => distances from Gram; e_i=0 => definitively NEW; stragglers
// resolved exactly in the last-block decide (T=0 for this data); lamb
// denominator = S[n] minus reassigned-sample densities.
// Coherence: all same-dispatch cross-block data is written AND read back via
// device-scope atomics (safe across non-coherent XCD L2s); plain-stored Dens
// is only read on the straggler path, guarded by __threadfence pairs.
// ---------------------------------------------------------------------------

#define DELTA_F 0.13533528323661270f  // float(exp(-2))
#define MBYTE (1u << 20)
#define ZRE_WORDS 16400

typedef __bf16 bf16;
typedef bf16 bf16x8 __attribute__((ext_vector_type(8)));
typedef bf16 bf16x4 __attribute__((ext_vector_type(4)));
typedef float f32x4 __attribute__((ext_vector_type(4)));

typedef __attribute__((address_space(1))) void as1_void;
typedef __attribute__((address_space(3))) void as3_void;

__device__ __forceinline__ void gload16(const bf16* g, bf16* l) {
  __builtin_amdgcn_global_load_lds((as1_void*)g, (as3_void*)l, 16, 0, 0);
}

__device__ __forceinline__ float wave_reduce(float s) {
  for (int o = 32; o > 0; o >>= 1) s += __shfl_down(s, o, 64);
  return s;
}

// ------------------------------- GEMM --------------------------------------
// C[2048, gridX*128] = A[2048,2048] * Bcat^T, 128x128 tiles, 8 waves =
// 2m x 2n x 2k, BK=64, XOR-swizzled LDS (swizzle on global source address;
// global_load_lds dest is lane-ordered). Gram blocks (bx<16) emit dens, S
// row sums, e flags, diag dens; sig blocks emit sigmoid (+SENh/colsumH, L0).
// The last-finishing block runs stau1(L0) + decide + lamb.
template <bool IS_L0>
__global__ __launch_bounds__(512, 4) void gemm_fused(
    const bf16* __restrict__ A, float* __restrict__ Dens,
    bf16* __restrict__ Hb, float* __restrict__ Fo,
    const float* __restrict__ bias, const float* __restrict__ SENin,
    const float* __restrict__ ninv_p, float* __restrict__ S,
    int* __restrict__ e, float* __restrict__ SENhOut,
    float* __restrict__ colsumH, float* __restrict__ diagD,
    int* __restrict__ cnt, float* __restrict__ scalOut,
    float* __restrict__ lambOut, int nblocks) {
  __shared__ __align__(16) char smem[32768];
  __shared__ int s_last;
  const int tid = threadIdx.x;
  const int wave = tid >> 6, lane = tid & 63;
  const int quad = lane >> 4, l16 = lane & 15;
  const int kg = wave & 1, wm = (wave >> 1) & 1, wn = (wave >> 2) & 1;
  const int m0 = blockIdx.y * 128, n0 = blockIdx.x * 128;
  const int waveM = wm * 64, waveN = wn * 64;
  const bool isGram = (n0 < 2048);
  const int sr8 = lane >> 3, slot = lane & 7;
  const int gk = (slot ^ sr8) * 8;  // swizzled global k-element offset
  const bf16* aSrc = A + (size_t)(m0 + wave * 16 + sr8) * 2048 + gk;
  const bf16* bSrc = A + (size_t)(n0 + wave * 16 + sr8) * 2048 + gk;
  char* const aDst = smem + wave * 2048;
  char* const bDst = smem + 16384 + wave * 2048;
  const int swz = ((kg * 4 + quad) ^ (l16 & 7)) * 16;
  const int aOff = (waveM + l16) * 128 + swz;
  const int bOff = 16384 + (waveN + l16) * 128 + swz;

  f32x4 acc[4][4] = {};
  for (int k0 = 0; k0 < 2048; k0 += 64) {
    gload16(aSrc + k0, (bf16*)aDst);
    gload16(aSrc + 8 * 2048 + k0, (bf16*)(aDst + 1024));
    gload16(bSrc + k0, (bf16*)bDst);
    gload16(bSrc + 8 * 2048 + k0, (bf16*)(bDst + 1024));
    __syncthreads();
    bf16x8 af[4], bfr[4];
#pragma unroll
    for (int i = 0; i < 4; ++i) af[i] = *(const bf16x8*)(smem + aOff + i * 2048);
#pragma unroll
    for (int j = 0; j < 4; ++j) bfr[j] = *(const bf16x8*)(smem + bOff + j * 2048);
#pragma unroll
    for (int i = 0; i < 4; ++i)
#pragma unroll
      for (int j = 0; j < 4; ++j)
        acc[i][j] = __builtin_amdgcn_mfma_f32_16x16x32_bf16(af[i], bfr[j], acc[i][j], 0, 0, 0);
    __syncthreads();
  }

  // epilogue: merge kg=1 partials into kg=0 via LDS (2 rounds of 2 i's)
  const float ninv = ninv_p[0];
  float colp[4] = {0.f, 0.f, 0.f, 0.f};
  char* const ex = smem + (wn * 2 + wm) * 8192;
#pragma unroll
  for (int round = 0; round < 2; ++round) {
    __syncthreads();
    if (kg == 1) {
#pragma unroll
      for (int ii = 0; ii < 2; ++ii)
#pragma unroll
        for (int j = 0; j < 4; ++j)
          *(f32x4*)(ex + (ii * 4 + j) * 1024 + lane * 16) = acc[round * 2 + ii][j];
    }
    __syncthreads();
    if (kg == 0) {
#pragma unroll
      for (int ii = 0; ii < 2; ++ii) {
        const int i = round * 2 + ii;
        const int rbase = m0 + waveM + i * 16 + quad * 4;
        if (isGram) {
          const f32x4 si4 = *(const f32x4*)(SENin + rbase);
          float rp[4] = {0.f, 0.f, 0.f, 0.f};
          int er = 0;
#pragma unroll
          for (int j = 0; j < 4; ++j) {
            f32x4 v = acc[i][j] + *(const f32x4*)(ex + (ii * 4 + j) * 1024 + lane * 16);
            const int col = n0 + waveN + j * 16 + l16;
            const float sj = SENin[col];
#pragma unroll
            for (int r = 0; r < 4; ++r) {
              const float dens = __expf((si4[r] + sj - 2.0f * v[r]) * ninv);
              Dens[(size_t)(rbase + r) * 2048 + col] = dens;
              rp[r] += dens;
              if (col < rbase + r && dens >= DELTA_F) er |= (1 << r);
              if (col == rbase + r) atomicExch(diagD + col, dens);
            }
          }
#pragma unroll
          for (int r = 0; r < 4; ++r) {
            float rv = rp[r];
            rv += __shfl_xor(rv, 1, 64); rv += __shfl_xor(rv, 2, 64);
            rv += __shfl_xor(rv, 4, 64); rv += __shfl_xor(rv, 8, 64);
            if (l16 == 0) atomicAdd(S + rbase + r, rv);
          }
          er |= __shfl_xor(er, 1, 64); er |= __shfl_xor(er, 2, 64);
          er |= __shfl_xor(er, 4, 64); er |= __shfl_xor(er, 8, 64);
          if (l16 == 0 && er) {
#pragma unroll
            for (int r = 0; r < 4; ++r)
              if ((er >> r) & 1) atomicOr(e + rbase + r, 1);
          }
        } else {
          float rn[4] = {0.f, 0.f, 0.f, 0.f};
#pragma unroll
          for (int j = 0; j < 4; ++j) {
            f32x4 v = acc[i][j] + *(const f32x4*)(ex + (ii * 4 + j) * 1024 + lane * 16);
            const int c2 = n0 - 2048 + waveN + j * 16 + l16;
            const float bv = bias[c2];
#pragma unroll
            for (int r = 0; r < 4; ++r) {
              const float hv = 1.0f / (1.0f + __expf(-(v[r] + bv)));
              if (IS_L0) {
                Hb[(size_t)(rbase + r) * 2048 + c2] = (bf16)hv;
                rn[r] += hv * hv;
                colp[j] += hv;
              } else {
                Fo[(size_t)(rbase + r) * 1024 + c2] = hv;
              }
            }
          }
          if (IS_L0) {
#pragma unroll
            for (int r = 0; r < 4; ++r) {
              float rv = rn[r];
              rv += __shfl_xor(rv, 1, 64); rv += __shfl_xor(rv, 2, 64);
              rv += __shfl_xor(rv, 4, 64); rv += __shfl_xor(rv, 8, 64);
              if (l16 == 0) atomicAdd(SENhOut + rbase + r, rv);
            }
          }
        }
      }
    }
  }
  if (IS_L0 && !isGram && kg == 0) {
#pragma unroll
    for (int j = 0; j < 4; ++j) {
      float cv = colp[j];
      cv += __shfl_xor(cv, 16, 64);
      cv += __shfl_xor(cv, 32, 64);
      if (lane < 16) atomicAdd(colsumH + (n0 - 2048 + waveN + j * 16 + lane), cv);
    }
  }

  // ---------------- done-counter: last block runs the tail -----------------
  __syncthreads();
  if (tid == 0) {
    __threadfence();
    s_last = (atomicAdd(cnt, 1) == nblocks - 1);
  }
  __syncthreads();
  if (!s_last) return;
  __threadfence();  // acquire: make other blocks' plain Dens stores visible

  // LDS overlays (gemm data dead now)
  char* s_flag = smem;                    // 2048
  short* s_as = (short*)(smem + 2048);    // 4096
  short* s_list = (short*)(smem + 6144);  // 4096
  short* s_re = (short*)(smem + 10240);   // 4096
  int* scan_ = (int*)(smem + 14336);      // 2048
  float* rbest = (float*)(smem + 16384);  // 2048
  int* rbj = (int*)(smem + 18432);        // 2048
  float* r1 = (float*)(smem + 20480);     // 2048
  float* r2 = (float*)(smem + 22528);     // 2048
  int* sT = (int*)(smem + 24576);
  int* sReN = (int*)(smem + 24580);

  if (IS_L0) {  // stau1 for layer 1 (SENh/colsumH atomic-written this grid)
    float ssen = 0.f, sg2 = 0.f;
    for (int i = tid; i < 2048; i += 512) ssen += atomicAdd(SENhOut + i, 0.f);
    for (int c = tid; c < 2048; c += 512) {
      const float gm = atomicAdd(colsumH + c, 0.f) * (1.f / 2048.f);
      sg2 += gm * gm;
    }
    r1[tid] = ssen; r2[tid] = sg2;
    __syncthreads();
    for (int s = 256; s; s >>= 1) {
      if (tid < s) { r1[tid] += r1[tid + s]; r2[tid] += r2[tid + s]; }
      __syncthreads();
    }
    if (tid == 0) {
      const float stau = 0.5f * (r1[0] * (1.f / 2048.f) - r2[0]);
      scalOut[4] = stau;
      scalOut[5] = -1.f / stau;
    }
    __syncthreads();
  }

  // ---- decide: prefix-sum compaction + exact sequential straggler pass ----
  int cntl = 0;
#pragma unroll
  for (int k = 0; k < 4; ++k) {
    const int i = tid * 4 + k;
    const int ei = atomicOr(e + i, 0);
    s_flag[i] = (ei == 0);
    if (ei == 0) s_as[i] = (short)i;
    cntl += (ei != 0);
  }
  scan_[tid] = cntl;
  if (tid == 0) sReN[0] = 0;
  __syncthreads();
  for (int off = 1; off < 512; off <<= 1) {
    const int v = scan_[tid];
    const int add = (tid >= off) ? scan_[tid - off] : 0;
    __syncthreads();
    scan_[tid] = v + add;
    __syncthreads();
  }
  int pos = scan_[tid] - cntl;
#pragma unroll
  for (int k = 0; k < 4; ++k) {
    const int i = tid * 4 + k;
    if (!s_flag[i]) s_list[pos++] = (short)i;
  }
  if (tid == 511) sT[0] = scan_[511];
  __syncthreads();
  const int T = sT[0];
  for (int t = 0; t < T; ++t) {
    const int i = s_list[t];
    const float* di = Dens + (size_t)i * 2048;
    float best = -1.0f;
    int bestj = 0x7fffffff;
    for (int j = tid; j < i; j += 512) {
      if (s_flag[j]) {
        const float d = di[j];
        if (d > best || (d == best && j < bestj)) { best = d; bestj = j; }
      }
    }
    rbest[tid] = best; rbj[tid] = bestj;
    __syncthreads();
    if (tid == 0) {
      float b = -1.0f;
      int bj = 0x7fffffff;
      for (int k = 0; k < 512; ++k)
        if (rbest[k] > b || (rbest[k] == b && rbj[k] < bj)) { b = rbest[k]; bj = rbj[k]; }
      if (b < DELTA_F) { s_flag[i] = 1; s_as[i] = (short)i; }
      else { s_as[i] = (short)bj; s_re[sReN[0]++] = (short)i; }
    }
    __syncthreads();
  }
  const int reN = sReN[0];

  // ---- lamb ----
#pragma unroll
  for (int k = 0; k < 4; ++k) {
    const int n = k * 512 + tid;
    const int aa = s_as[n];
    const float num = (aa == n) ? atomicAdd(diagD + n, 0.f)
                                : Dens[(size_t)n * 2048 + aa];
    float denom = atomicAdd(S + n, 0.f);
    for (int t = 0; t < reN; ++t) denom -= Dens[(size_t)n * 2048 + s_re[t]];
    lambOut[n] = num / denom;
  }
}

// --------------------------- small kernels ---------------------------------
// grid 640: b<256 x-rows (convert+SENx+private colsum row); b<512 W0;
// else W1 (+zero the accumulator region, consumed by later dispatches only)
__global__ void f2b_all(const float* __restrict__ x, const float* __restrict__ W0,
                        const float* __restrict__ W1, bf16* __restrict__ xb,
                        bf16* __restrict__ wb0, bf16* __restrict__ wb1,
                        float* __restrict__ SENx, float* __restrict__ cpart,
                        int* __restrict__ zre) {
  const int b = blockIdx.x, tid = threadIdx.x;
  const int wave = tid >> 6, lane = tid & 63;
  if (b < 256) {
    const int r0 = b * 8;
    __shared__ float ws[8][4];
    f32x4 c0 = {0.f, 0.f, 0.f, 0.f}, c1 = {0.f, 0.f, 0.f, 0.f};
    for (int r = 0; r < 8; ++r) {
      const float* src = x + (size_t)(r0 + r) * 2048;
      bf16* dst = xb + (size_t)(r0 + r) * 2048;
      f32x4 v0 = *(const f32x4*)(src + tid * 4);
      f32x4 v1 = *(const f32x4*)(src + 1024 + tid * 4);
      bf16x4 o0, o1;
      o0.x = (bf16)v0.x; o0.y = (bf16)v0.y; o0.z = (bf16)v0.z; o0.w = (bf16)v0.w;
      o1.x = (bf16)v1.x; o1.y = (bf16)v1.y; o1.z = (bf16)v1.z; o1.w = (bf16)v1.w;
      *(bf16x4*)(dst + tid * 4) = o0;
      *(bf16x4*)(dst + 1024 + tid * 4) = o1;
      c0 += v0; c1 += v1;
      float rn = v0.x * v0.x + v0.y * v0.y + v0.z * v0.z + v0.w * v0.w +
                 v1.x * v1.x + v1.y * v1.y + v1.z * v1.z + v1.w * v1.w;
      rn = wave_reduce(rn);
      if (lane == 0) ws[r][wave] = rn;
    }
    __syncthreads();
    if (tid < 8) SENx[r0 + tid] = ws[tid][0] + ws[tid][1] + ws[tid][2] + ws[tid][3];
    float* bin = cpart + (size_t)b * 2048;  // private row: no atomics
    *(f32x4*)(bin + tid * 4) = c0;
    *(f32x4*)(bin + 1024 + tid * 4) = c1;
  } else if (b < 512) {
    const size_t base = (size_t)(b - 256) * 16384;
    for (int c = tid * 4; c < 16384; c += 1024) {
      f32x4 v = *(const f32x4*)(W0 + base + c);
      bf16x4 o;
      o.x = (bf16)v.x; o.y = (bf16)v.y; o.z = (bf16)v.z; o.w = (bf16)v.w;
      *(bf16x4*)(wb0 + base + c) = o;
    }
  } else {
    const size_t base = (size_t)(b - 512) * 16384;
    for (int c = tid * 4; c < 16384; c += 1024) {
      f32x4 v = *(const f32x4*)(W1 + base + c);
      bf16x4 o;
      o.x = (bf16)v.x; o.y = (bf16)v.y; o.z = (bf16)v.z; o.w = (bf16)v.w;
      *(bf16x4*)(wb1 + base + c) = o;
    }
    const int idx = (b - 512) * 256 + tid;
    if (idx < ZRE_WORDS) zre[idx] = 0;
  }
}

// 8 blocks: block p sums cols [p*256,p*256+256) of the 256 colsum partials;
// block 0 also sums SENx; last block computes scal[0]=stau0, scal[1]=-1/stau0
__global__ void stau0_kernel(const float* __restrict__ SENx,
                             const float* __restrict__ cpart,
                             float* __restrict__ accS, float* __restrict__ accG,
                             int* __restrict__ cntS, float* __restrict__ scal) {
  const int p = blockIdx.x, tid = threadIdx.x;
  const int col = p * 256 + tid;
  float s = 0.f;
  for (int r = 0; r < 256; ++r) s += cpart[(size_t)r * 2048 + col];
  const float gm = s * (1.f / 2048.f);
  float sg2 = gm * gm;
  float ssen = 0.f;
  if (p == 0)
    for (int i = tid; i < 2048; i += 256) ssen += SENx[i];
  __shared__ float r1[256], r2[256];
  __shared__ int s_last;
  r1[tid] = sg2; r2[tid] = ssen;
  __syncthreads();
  for (int st = 128; st; st >>= 1) {
    if (tid < st) { r1[tid] += r1[tid + st]; r2[tid] += r2[tid + st]; }
    __syncthreads();
  }
  if (tid == 0) {
    atomicAdd(accG, r1[0]);
    if (p == 0) atomicAdd(accS, r2[0]);
    __threadfence();
    s_last = (atomicAdd(cntS, 1) == 7);
  }
  __syncthreads();
  if (tid == 0 && s_last) {
    const float vG = atomicAdd(accG, 0.f);
    const float vS = atomicAdd(accS, 0.f);
    const float stau = 0.5f * (vS * (1.f / 2048.f) - vG);
    scal[0] = stau;
    scal[1] = -1.f / stau;
  }
}

// ------------------------------- driver ------------------------------------
extern "C" void kernel_launch(void* const* d_in, const int* in_sizes, int n_in,
                              void* d_out, int out_size, void* d_ws, size_t ws_size,
                              hipStream_t stream) {
  const float* x = (const float*)d_in[0];
  const float* W0 = (const float*)d_in[1];
  const float* b0 = (const float*)d_in[2];
  const float* W1 = (const float*)d_in[3];
  const float* b1 = (const float*)d_in[4];
  float* out = (float*)d_out;

  char* w = (char*)d_ws;
  bf16* xb = (bf16*)(w);                   // 8 MB  [L0 rows 0..2047]
  bf16* wb0 = (bf16*)(w + 8 * MBYTE);      // 8 MB  [L0 rows 2048..4095]
  bf16* hb = (bf16*)(w + 16 * MBYTE);      // 8 MB  [L1 rows 0..2047]
  bf16* wb1 = (bf16*)(w + 24 * MBYTE);     // 4 MB  [L1 rows 2048..3071]
  float* Dens = (float*)(w + 28 * MBYTE);  // 16 MB
  float* SENx = (float*)(w + 44 * MBYTE);  // 2048 (plain; cross-dispatch)
  float* cpart = SENx + 2048;              // 256*2048 private colsum rows
  float* scal = cpart + 256 * 2048;        // 16: [0,1]=L0 stau,-1/stau [4,5]=L1
  float* zre = scal + 16;                  // ---- zeroed accumulator region ----
  float* SENh = zre;                       // 2048
  float* colsumH = SENh + 2048;            // 2048
  float* S0 = colsumH + 2048;              // 2048
  float* S1 = S0 + 2048;                   // 2048
  float* diagD0 = S1 + 2048;               // 2048
  float* diagD1 = diagD0 + 2048;           // 2048
  int* e0 = (int*)(diagD1 + 2048);         // 2048
  int* e1 = e0 + 2048;                     // 2048
  float* accS = (float*)(e1 + 2048);
  float* accG = accS + 1;
  int* cntS = (int*)(accG + 1);
  int* cnt0 = cntS + 1;
  int* cnt1 = cnt0 + 1;

  float* lamb0 = out + (size_t)2048 * 1024;
  float* lamb1 = lamb0 + 2048;

  f2b_all<<<640, 256, 0, stream>>>(x, W0, W1, xb, wb0, wb1, SENx, cpart, (int*)zre);
  stau0_kernel<<<8, 256, 0, stream>>>(SENx, cpart, accS, accG, cntS, scal);
  gemm_fused<true><<<dim3(32, 16), 512, 0, stream>>>(
      xb, Dens, hb, nullptr, b0, SENx, scal + 1, S0, e0, SENh, colsumH,
      diagD0, cnt0, scal, lamb0, 512);
  gemm_fused<false><<<dim3(24, 16), 512, 0, stream>>>(
      hb, Dens, nullptr, out, b1, SENh, scal + 5, S1, e1, nullptr, nullptr,
      diagD1, cnt1, nullptr, lamb1, 384);
}

// Round 9
// 203.400 us; speedup vs baseline: 1.1302x; 1.1302x over previous
//
#include <hip/hip_runtime.h>
#include <cstdint>
#include <cstddef>

// ---------------------------------------------------------------------------
// SOMFNN forward, 4 dispatches:
//   0. memset    : zero the atomic-accumulator region (196 KB)
//   1. f2b_all   : convert x/W0/W1 to bf16; SENx (atomicExch) + colsum bins
//                  (atomicAdd); LAST block (done-counter) computes stau0
//   2. gemm L0   : fused Gram(dens,S,e,diag)+sigmoid(hb,SENh,colsumH); last
//                  block runs stau1 + decide0 + lamb0
//   3. gemm L1   : fused Gram+sigmoid(out); last block runs decide1 + lamb1
//
// R8 post-mortem: per-block __threadfence (agent release -> L2 writeback of
// ~64MB dirty gemm output across 512 blocks) cost +25-35us per gemm. R9
// removes ALL same-dispatch fences: every cross-block datum on the common
// path is published via device-scope atomics, and __syncthreads() drains
// vmcnt(0) for all waves before the done-counter increment, so the last
// block observing cnt==nb-1 proves all prior atomics completed. Plain-stored
// Dens is only read on the straggler path (T>0; never for this data) which
// keeps a best-effort __threadfence inside that branch.
//
// Semantics (exact vs reference): stau=base/2 scalar (SENc==cn2); prototypes
// never updated => distances from Gram; e_i=0 => definitively NEW;
// stragglers resolved sequentially in the tail; lamb = dens(n,assigned)
// / (S[n] - reassigned-sample densities).
// ---------------------------------------------------------------------------

#define DELTA_F 0.13533528323661270f  // float(exp(-2))
#define MBYTE (1u << 20)

typedef __bf16 bf16;
typedef bf16 bf16x8 __attribute__((ext_vector_type(8)));
typedef bf16 bf16x4 __attribute__((ext_vector_type(4)));
typedef float f32x4 __attribute__((ext_vector_type(4)));

typedef __attribute__((address_space(1))) void as1_void;
typedef __attribute__((address_space(3))) void as3_void;

__device__ __forceinline__ void gload16(const bf16* g, bf16* l) {
  __builtin_amdgcn_global_load_lds((as1_void*)g, (as3_void*)l, 16, 0, 0);
}

__device__ __forceinline__ float wave_reduce(float s) {
  for (int o = 32; o > 0; o >>= 1) s += __shfl_down(s, o, 64);
  return s;
}

// ------------------------------- GEMM --------------------------------------
// C[2048, gridX*128] = A[2048,2048] * Bcat^T, 128x128 tiles, 8 waves =
// 2m x 2n x 2k, BK=64, XOR-swizzled LDS (swizzle on global source address;
// global_load_lds dest is lane-ordered). Gram blocks (bx<16) emit dens, S
// row sums, e flags, diag dens (all atomics); sig blocks emit sigmoid
// (+SENh/colsumH atomics, L0). Last block (fence-free done-counter) runs
// stau1(L0) + decide + lamb.
template <bool IS_L0>
__global__ __launch_bounds__(512, 4) void gemm_fused(
    const bf16* __restrict__ A, float* __restrict__ Dens,
    bf16* __restrict__ Hb, float* __restrict__ Fo,
    const float* __restrict__ bias, const float* __restrict__ SENin,
    const float* __restrict__ ninv_p, float* __restrict__ S,
    int* __restrict__ e, float* __restrict__ SENhOut,
    float* __restrict__ colsumH, float* __restrict__ diagD,
    int* __restrict__ cnt, float* __restrict__ scalOut,
    float* __restrict__ lambOut, int nblocks) {
  __shared__ __align__(16) char smem[32768];
  __shared__ int s_last;
  const int tid = threadIdx.x;
  const int wave = tid >> 6, lane = tid & 63;
  const int quad = lane >> 4, l16 = lane & 15;
  const int kg = wave & 1, wm = (wave >> 1) & 1, wn = (wave >> 2) & 1;
  const int m0 = blockIdx.y * 128, n0 = blockIdx.x * 128;
  const int waveM = wm * 64, waveN = wn * 64;
  const bool isGram = (n0 < 2048);
  const int sr8 = lane >> 3, slot = lane & 7;
  const int gk = (slot ^ sr8) * 8;  // swizzled global k-element offset
  const bf16* aSrc = A + (size_t)(m0 + wave * 16 + sr8) * 2048 + gk;
  const bf16* bSrc = A + (size_t)(n0 + wave * 16 + sr8) * 2048 + gk;
  char* const aDst = smem + wave * 2048;
  char* const bDst = smem + 16384 + wave * 2048;
  const int swz = ((kg * 4 + quad) ^ (l16 & 7)) * 16;
  const int aOff = (waveM + l16) * 128 + swz;
  const int bOff = 16384 + (waveN + l16) * 128 + swz;

  f32x4 acc[4][4] = {};
  for (int k0 = 0; k0 < 2048; k0 += 64) {
    gload16(aSrc + k0, (bf16*)aDst);
    gload16(aSrc + 8 * 2048 + k0, (bf16*)(aDst + 1024));
    gload16(bSrc + k0, (bf16*)bDst);
    gload16(bSrc + 8 * 2048 + k0, (bf16*)(bDst + 1024));
    __syncthreads();
    bf16x8 af[4], bfr[4];
#pragma unroll
    for (int i = 0; i < 4; ++i) af[i] = *(const bf16x8*)(smem + aOff + i * 2048);
#pragma unroll
    for (int j = 0; j < 4; ++j) bfr[j] = *(const bf16x8*)(smem + bOff + j * 2048);
#pragma unroll
    for (int i = 0; i < 4; ++i)
#pragma unroll
      for (int j = 0; j < 4; ++j)
        acc[i][j] = __builtin_amdgcn_mfma_f32_16x16x32_bf16(af[i], bfr[j], acc[i][j], 0, 0, 0);
    __syncthreads();
  }

  // epilogue: merge kg=1 partials into kg=0 via LDS (2 rounds of 2 i's)
  const float ninv = ninv_p[0];
  float colp[4] = {0.f, 0.f, 0.f, 0.f};
  char* const ex = smem + (wn * 2 + wm) * 8192;
#pragma unroll
  for (int round = 0; round < 2; ++round) {
    __syncthreads();
    if (kg == 1) {
#pragma unroll
      for (int ii = 0; ii < 2; ++ii)
#pragma unroll
        for (int j = 0; j < 4; ++j)
          *(f32x4*)(ex + (ii * 4 + j) * 1024 + lane * 16) = acc[round * 2 + ii][j];
    }
    __syncthreads();
    if (kg == 0) {
#pragma unroll
      for (int ii = 0; ii < 2; ++ii) {
        const int i = round * 2 + ii;
        const int rbase = m0 + waveM + i * 16 + quad * 4;
        if (isGram) {
          const f32x4 si4 = *(const f32x4*)(SENin + rbase);
          float rp[4] = {0.f, 0.f, 0.f, 0.f};
          int er = 0;
#pragma unroll
          for (int j = 0; j < 4; ++j) {
            f32x4 v = acc[i][j] + *(const f32x4*)(ex + (ii * 4 + j) * 1024 + lane * 16);
            const int col = n0 + waveN + j * 16 + l16;
            const float sj = SENin[col];
#pragma unroll
            for (int r = 0; r < 4; ++r) {
              const float dens = __expf((si4[r] + sj - 2.0f * v[r]) * ninv);
              Dens[(size_t)(rbase + r) * 2048 + col] = dens;
              rp[r] += dens;
              if (col < rbase + r && dens >= DELTA_F) er |= (1 << r);
              if (col == rbase + r) atomicExch(diagD + col, dens);
            }
          }
#pragma unroll
          for (int r = 0; r < 4; ++r) {
            float rv = rp[r];
            rv += __shfl_xor(rv, 1, 64); rv += __shfl_xor(rv, 2, 64);
            rv += __shfl_xor(rv, 4, 64); rv += __shfl_xor(rv, 8, 64);
            if (l16 == 0) atomicAdd(S + rbase + r, rv);
          }
          er |= __shfl_xor(er, 1, 64); er |= __shfl_xor(er, 2, 64);
          er |= __shfl_xor(er, 4, 64); er |= __shfl_xor(er, 8, 64);
          if (l16 == 0 && er) {
#pragma unroll
            for (int r = 0; r < 4; ++r)
              if ((er >> r) & 1) atomicOr(e + rbase + r, 1);
          }
        } else {
          float rn[4] = {0.f, 0.f, 0.f, 0.f};
#pragma unroll
          for (int j = 0; j < 4; ++j) {
            f32x4 v = acc[i][j] + *(const f32x4*)(ex + (ii * 4 + j) * 1024 + lane * 16);
            const int c2 = n0 - 2048 + waveN + j * 16 + l16;
            const float bv = bias[c2];
#pragma unroll
            for (int r = 0; r < 4; ++r) {
              const float hv = 1.0f / (1.0f + __expf(-(v[r] + bv)));
              if (IS_L0) {
                Hb[(size_t)(rbase + r) * 2048 + c2] = (bf16)hv;
                rn[r] += hv * hv;
                colp[j] += hv;
              } else {
                Fo[(size_t)(rbase + r) * 1024 + c2] = hv;
              }
            }
          }
          if (IS_L0) {
#pragma unroll
            for (int r = 0; r < 4; ++r) {
              float rv = rn[r];
              rv += __shfl_xor(rv, 1, 64); rv += __shfl_xor(rv, 2, 64);
              rv += __shfl_xor(rv, 4, 64); rv += __shfl_xor(rv, 8, 64);
              if (l16 == 0) atomicAdd(SENhOut + rbase + r, rv);
            }
          }
        }
      }
    }
  }
  if (IS_L0 && !isGram && kg == 0) {
#pragma unroll
    for (int j = 0; j < 4; ++j) {
      float cv = colp[j];
      cv += __shfl_xor(cv, 16, 64);
      cv += __shfl_xor(cv, 32, 64);
      if (lane < 16) atomicAdd(colsumH + (n0 - 2048 + waveN + j * 16 + lane), cv);
    }
  }

  // ---- fence-free done-counter: __syncthreads drains vmcnt(0) for all
  // waves, so prior atomics are complete before the increment. ----
  __syncthreads();
  if (tid == 0) s_last = (atomicAdd(cnt, 1) == nblocks - 1);
  __syncthreads();
  if (!s_last) return;

  // LDS overlays (gemm data dead now)
  char* s_flag = smem;                    // 2048
  short* s_as = (short*)(smem + 2048);    // 4096
  short* s_list = (short*)(smem + 6144);  // 4096
  short* s_re = (short*)(smem + 10240);   // 4096
  int* scan_ = (int*)(smem + 14336);      // 2048
  float* rbest = (float*)(smem + 16384);  // 2048
  int* rbj = (int*)(smem + 18432);        // 2048
  float* r1 = (float*)(smem + 20480);     // 2048
  float* r2 = (float*)(smem + 22528);     // 2048
  int* sT = (int*)(smem + 24576);
  int* sReN = (int*)(smem + 24580);

  if (IS_L0) {  // stau1 (SENh/colsumH atomic-written this grid -> atomic-read)
    float ssen = 0.f, sg2 = 0.f;
    for (int i = tid; i < 2048; i += 512) ssen += atomicAdd(SENhOut + i, 0.f);
    for (int c = tid; c < 2048; c += 512) {
      const float gm = atomicAdd(colsumH + c, 0.f) * (1.f / 2048.f);
      sg2 += gm * gm;
    }
    r1[tid] = ssen; r2[tid] = sg2;
    __syncthreads();
    for (int s = 256; s; s >>= 1) {
      if (tid < s) { r1[tid] += r1[tid + s]; r2[tid] += r2[tid + s]; }
      __syncthreads();
    }
    if (tid == 0) {
      const float stau = 0.5f * (r1[0] * (1.f / 2048.f) - r2[0]);
      scalOut[4] = stau;
      scalOut[5] = -1.f / stau;
    }
    __syncthreads();
  }

  // ---- decide: prefix-sum compaction + exact sequential straggler pass ----
  int cntl = 0;
#pragma unroll
  for (int k = 0; k < 4; ++k) {
    const int i = tid * 4 + k;
    const int ei = atomicOr(e + i, 0);
    s_flag[i] = (ei == 0);
    if (ei == 0) s_as[i] = (short)i;
    cntl += (ei != 0);
  }
  scan_[tid] = cntl;
  if (tid == 0) sReN[0] = 0;
  __syncthreads();
  for (int off = 1; off < 512; off <<= 1) {
    const int v = scan_[tid];
    const int add = (tid >= off) ? scan_[tid - off] : 0;
    __syncthreads();
    scan_[tid] = v + add;
    __syncthreads();
  }
  int pos = scan_[tid] - cntl;
#pragma unroll
  for (int k = 0; k < 4; ++k) {
    const int i = tid * 4 + k;
    if (!s_flag[i]) s_list[pos++] = (short)i;
  }
  if (tid == 511) sT[0] = scan_[511];
  __syncthreads();
  const int T = sT[0];
  if (T > 0) __threadfence();  // straggler path only (never for this data)
  for (int t = 0; t < T; ++t) {
    const int i = s_list[t];
    const float* di = Dens + (size_t)i * 2048;
    float best = -1.0f;
    int bestj = 0x7fffffff;
    for (int j = tid; j < i; j += 512) {
      if (s_flag[j]) {
        const float d = di[j];
        if (d > best || (d == best && j < bestj)) { best = d; bestj = j; }
      }
    }
    rbest[tid] = best; rbj[tid] = bestj;
    __syncthreads();
    if (tid == 0) {
      float b = -1.0f;
      int bj = 0x7fffffff;
      for (int k = 0; k < 512; ++k)
        if (rbest[k] > b || (rbest[k] == b && rbj[k] < bj)) { b = rbest[k]; bj = rbj[k]; }
      if (b < DELTA_F) { s_flag[i] = 1; s_as[i] = (short)i; }
      else { s_as[i] = (short)bj; s_re[sReN[0]++] = (short)i; }
    }
    __syncthreads();
  }
  const int reN = sReN[0];

  // ---- lamb ----
#pragma unroll
  for (int k = 0; k < 4; ++k) {
    const int n = k * 512 + tid;
    const int aa = s_as[n];
    const float num = (aa == n) ? atomicAdd(diagD + n, 0.f)
                                : Dens[(size_t)n * 2048 + aa];
    float denom = atomicAdd(S + n, 0.f);
    for (int t = 0; t < reN; ++t) denom -= Dens[(size_t)n * 2048 + s_re[t]];
    lambOut[n] = num / denom;
  }
}

// --------------------------- small kernels ---------------------------------
// grid 640: b<256 x-rows (convert + SENx atomicExch + 16-bin atomic colsum);
// b<512 W0 convert; else W1 convert. Last block computes stau0 (fence-free).
__global__ void f2b_all(const float* __restrict__ x, const float* __restrict__ W0,
                        const float* __restrict__ W1, bf16* __restrict__ xb,
                        bf16* __restrict__ wb0, bf16* __restrict__ wb1,
                        float* __restrict__ SENx, float* __restrict__ bins,
                        int* __restrict__ cntF, float* __restrict__ scal) {
  const int b = blockIdx.x, tid = threadIdx.x;
  const int wave = tid >> 6, lane = tid & 63;
  __shared__ float ws[8][4];
  __shared__ float red1[256], red2[256];
  __shared__ int s_last;
  if (b < 256) {
    const int r0 = b * 8;
    f32x4 c0 = {0.f, 0.f, 0.f, 0.f}, c1 = {0.f, 0.f, 0.f, 0.f};
    for (int r = 0; r < 8; ++r) {
      const float* src = x + (size_t)(r0 + r) * 2048;
      bf16* dst = xb + (size_t)(r0 + r) * 2048;
      f32x4 v0 = *(const f32x4*)(src + tid * 4);
      f32x4 v1 = *(const f32x4*)(src + 1024 + tid * 4);
      bf16x4 o0, o1;
      o0.x = (bf16)v0.x; o0.y = (bf16)v0.y; o0.z = (bf16)v0.z; o0.w = (bf16)v0.w;
      o1.x = (bf16)v1.x; o1.y = (bf16)v1.y; o1.z = (bf16)v1.z; o1.w = (bf16)v1.w;
      *(bf16x4*)(dst + tid * 4) = o0;
      *(bf16x4*)(dst + 1024 + tid * 4) = o1;
      c0 += v0; c1 += v1;
      float rn = v0.x * v0.x + v0.y * v0.y + v0.z * v0.z + v0.w * v0.w +
                 v1.x * v1.x + v1.y * v1.y + v1.z * v1.z + v1.w * v1.w;
      rn = wave_reduce(rn);
      if (lane == 0) ws[r][wave] = rn;
    }
    __syncthreads();
    if (tid < 8)
      atomicExch(SENx + r0 + tid, ws[tid][0] + ws[tid][1] + ws[tid][2] + ws[tid][3]);
    float* bin = bins + (size_t)(b & 15) * 2048;
    atomicAdd(bin + tid * 4 + 0, c0.x); atomicAdd(bin + tid * 4 + 1, c0.y);
    atomicAdd(bin + tid * 4 + 2, c0.z); atomicAdd(bin + tid * 4 + 3, c0.w);
    atomicAdd(bin + 1024 + tid * 4 + 0, c1.x); atomicAdd(bin + 1024 + tid * 4 + 1, c1.y);
    atomicAdd(bin + 1024 + tid * 4 + 2, c1.z); atomicAdd(bin + 1024 + tid * 4 + 3, c1.w);
  } else if (b < 512) {
    const size_t base = (size_t)(b - 256) * 16384;
    for (int c = tid * 4; c < 16384; c += 1024) {
      f32x4 v = *(const f32x4*)(W0 + base + c);
      bf16x4 o;
      o.x = (bf16)v.x; o.y = (bf16)v.y; o.z = (bf16)v.z; o.w = (bf16)v.w;
      *(bf16x4*)(wb0 + base + c) = o;
    }
  } else {
    const size_t base = (size_t)(b - 512) * 16384;
    for (int c = tid * 4; c < 16384; c += 1024) {
      f32x4 v = *(const f32x4*)(W1 + base + c);
      bf16x4 o;
      o.x = (bf16)v.x; o.y = (bf16)v.y; o.z = (bf16)v.z; o.w = (bf16)v.w;
      *(bf16x4*)(wb1 + base + c) = o;
    }
  }

  // fence-free done-counter finisher: stau0
  __syncthreads();
  if (tid == 0) s_last = (atomicAdd(cntF, 1) == 639);
  __syncthreads();
  if (!s_last) return;
  float ssen = 0.f;
  for (int i = tid; i < 2048; i += 256) ssen += atomicAdd(SENx + i, 0.f);
  float sg2 = 0.f;
  for (int c = tid; c < 2048; c += 256) {
    float cs = 0.f;
#pragma unroll
    for (int p = 0; p < 16; ++p) cs += atomicAdd(bins + (size_t)p * 2048 + c, 0.f);
    const float gm = cs * (1.f / 2048.f);
    sg2 += gm * gm;
  }
  red1[tid] = ssen; red2[tid] = sg2;
  __syncthreads();
  for (int s = 128; s; s >>= 1) {
    if (tid < s) { red1[tid] += red1[tid + s]; red2[tid] += red2[tid + s]; }
    __syncthreads();
  }
  if (tid == 0) {
    const float stau = 0.5f * (red1[0] * (1.f / 2048.f) - red2[0]);
    scal[0] = stau;
    scal[1] = -1.f / stau;
  }
}

// ------------------------------- driver ------------------------------------
extern "C" void kernel_launch(void* const* d_in, const int* in_sizes, int n_in,
                              void* d_out, int out_size, void* d_ws, size_t ws_size,
                              hipStream_t stream) {
  const float* x = (const float*)d_in[0];
  const float* W0 = (const float*)d_in[1];
  const float* b0 = (const float*)d_in[2];
  const float* W1 = (const float*)d_in[3];
  const float* b1 = (const float*)d_in[4];
  float* out = (float*)d_out;

  char* w = (char*)d_ws;
  bf16* xb = (bf16*)(w);                   // 8 MB  [L0 rows 0..2047]
  bf16* wb0 = (bf16*)(w + 8 * MBYTE);      // 8 MB  [L0 rows 2048..4095]
  bf16* hb = (bf16*)(w + 16 * MBYTE);      // 8 MB  [L1 rows 0..2047]
  bf16* wb1 = (bf16*)(w + 24 * MBYTE);     // 4 MB  [L1 rows 2048..3071]
  float* Dens = (float*)(w + 28 * MBYTE);  // 16 MB
  float* SENx = (float*)(w + 44 * MBYTE);  // 2048 (atomicExch; no zero needed)
  float* scal = SENx + 2048;               // 16: [0,1]=L0 stau,-1/stau [4,5]=L1
  // ---- zeroed accumulator region (one memset node) ----
  float* zre = scal + 16;
  float* bins = zre;                       // 16*2048 colsum bins
  float* SENh = bins + 16 * 2048;          // 2048
  float* colsumH = SENh + 2048;            // 2048
  float* S0 = colsumH + 2048;              // 2048
  float* S1 = S0 + 2048;                   // 2048
  float* diagD0 = S1 + 2048;               // 2048
  float* diagD1 = diagD0 + 2048;           // 2048
  int* e0 = (int*)(diagD1 + 2048);         // 2048
  int* e1 = e0 + 2048;                     // 2048
  int* cntF = e1 + 2048;
  int* cnt0 = cntF + 1;
  int* cnt1 = cnt0 + 1;
  const size_t zwords = 16 * 2048 + 8 * 2048 + 16;

  float* lamb0 = out + (size_t)2048 * 1024;
  float* lamb1 = lamb0 + 2048;

  hipMemsetAsync(zre, 0, zwords * 4, stream);
  f2b_all<<<640, 256, 0, stream>>>(x, W0, W1, xb, wb0, wb1, SENx, bins, cntF, scal);
  gemm_fused<true><<<dim3(32, 16), 512, 0, stream>>>(
      xb, Dens, hb, nullptr, b0, SENx, scal + 1, S0, e0, SENh, colsumH,
      diagD0, cnt0, scal, lamb0, 512);
  gemm_fused<false><<<dim3(24, 16), 512, 0, stream>>>(
      hb, Dens, nullptr, out, b1, SENh, scal + 5, S1, e1, nullptr, nullptr,
      diagD1, cnt1, nullptr, lamb1, 384);
}

// Round 10
// 195.185 us; speedup vs baseline: 1.1778x; 1.0421x over previous
//
#include <hip/hip_runtime.h>
#include <cstdint>
#include <cstddef>

// ---------------------------------------------------------------------------
// SOMFNN forward, 4 dispatches:
//   0. memset    : zero the atomic-accumulator region (~196 KB)
//   1. f2b_all   : convert x/W0/W1 to bf16; SENx + colsum bins; last block
//                  (fence-free done-counter) computes stau0
//   2. gemm L0   : fused Gram(dens,S0,e0,diag0)+sigmoid(hb,SENh,colsumH).
//                  NO tail (R9's embedded tail serialized ~10us at dispatch
//                  end; moved to a concurrent block in dispatch 3).
//   3. gemm L1   : 384 gemm blocks (Gram+sigmoid->out) + ONE tail-0 block
//                  (bx==24,by==0) that concurrently computes stau1 (publishes
//                  ninv1 as the value of a ready-flag via one atomicExch),
//                  then decide0+lamb0 from dispatch-2 outputs (plain reads,
//                  cross-dispatch safe). Gram blocks spin the flag at
//                  epilogue (~40us in; set at ~3us -> zero iterations).
//                  Last gemm block (done-counter) runs decide1+lamb1.
// Buffer rotation: Dens1 overwrites the dead xb+wb0 region (w+0) so Dens0
// (w+28MB) stays intact for the concurrent decide0.
// Coherence: same-dispatch cross-block data only via device-scope atomics
// (fence-free done-counter: __syncthreads drains vmcnt(0) first); plain
// Dens reads only cross-dispatch or behind the straggler fence.
// Semantics (exact vs reference): stau=base/2 scalar (SENc==cn2); prototypes
// never updated => distances from Gram; e_i=0 => definitively NEW;
// stragglers resolved sequentially (T=0 for this data); lamb =
// dens(n,assigned)/(S[n] - reassigned densities).
// ---------------------------------------------------------------------------

#define DELTA_F 0.13533528323661270f  // float(exp(-2))
#define MBYTE (1u << 20)

typedef __bf16 bf16;
typedef bf16 bf16x8 __attribute__((ext_vector_type(8)));
typedef bf16 bf16x4 __attribute__((ext_vector_type(4)));
typedef float f32x4 __attribute__((ext_vector_type(4)));

typedef __attribute__((address_space(1))) void as1_void;
typedef __attribute__((address_space(3))) void as3_void;

__device__ __forceinline__ void gload16(const bf16* g, bf16* l) {
  __builtin_amdgcn_global_load_lds((as1_void*)g, (as3_void*)l, 16, 0, 0);
}

__device__ __forceinline__ float wave_reduce(float s) {
  for (int o = 32; o > 0; o >>= 1) s += __shfl_down(s, o, 64);
  return s;
}

// ---- shared decide+lamb tail. SAME=true: data written by THIS dispatch
// (atomic reads; fence only on straggler path). SAME=false: previous
// dispatch (plain reads). smem needs >= 24584 bytes. ----
template <bool SAME>
__device__ void run_decide_lamb(char* smem, int* e, float* Dens, float* S,
                                float* diagD, float* lambOut) {
  char* s_flag = smem;                    // 2048
  short* s_as = (short*)(smem + 2048);    // 4096
  short* s_list = (short*)(smem + 6144);  // 4096
  short* s_re = (short*)(smem + 10240);   // 4096
  int* scan_ = (int*)(smem + 14336);      // 2048
  float* rbest = (float*)(smem + 16384);  // 2048
  int* rbj = (int*)(smem + 18432);        // 2048
  int* sT = (int*)(smem + 24576);
  int* sReN = (int*)(smem + 24580);
  const int tid = threadIdx.x;
  int cntl = 0;
#pragma unroll
  for (int k = 0; k < 4; ++k) {
    const int i = tid * 4 + k;
    const int ei = SAME ? atomicOr(e + i, 0) : e[i];
    s_flag[i] = (ei == 0);
    if (ei == 0) s_as[i] = (short)i;
    cntl += (ei != 0);
  }
  scan_[tid] = cntl;
  if (tid == 0) sReN[0] = 0;
  __syncthreads();
  for (int off = 1; off < 512; off <<= 1) {
    const int v = scan_[tid];
    const int add = (tid >= off) ? scan_[tid - off] : 0;
    __syncthreads();
    scan_[tid] = v + add;
    __syncthreads();
  }
  int pos = scan_[tid] - cntl;
#pragma unroll
  for (int k = 0; k < 4; ++k) {
    const int i = tid * 4 + k;
    if (!s_flag[i]) s_list[pos++] = (short)i;
  }
  if (tid == 511) sT[0] = scan_[511];
  __syncthreads();
  const int T = sT[0];
  if (SAME && T > 0) __threadfence();  // straggler path only (rare)
  for (int t = 0; t < T; ++t) {
    const int i = s_list[t];
    const float* di = Dens + (size_t)i * 2048;
    float best = -1.0f;
    int bestj = 0x7fffffff;
    for (int j = tid; j < i; j += 512) {
      if (s_flag[j]) {
        const float d = di[j];
        if (d > best || (d == best && j < bestj)) { best = d; bestj = j; }
      }
    }
    rbest[tid] = best; rbj[tid] = bestj;
    __syncthreads();
    if (tid == 0) {
      float b = -1.0f;
      int bj = 0x7fffffff;
      for (int k = 0; k < 512; ++k)
        if (rbest[k] > b || (rbest[k] == b && rbj[k] < bj)) { b = rbest[k]; bj = rbj[k]; }
      if (b < DELTA_F) { s_flag[i] = 1; s_as[i] = (short)i; }
      else { s_as[i] = (short)bj; s_re[sReN[0]++] = (short)i; }
    }
    __syncthreads();
  }
  const int reN = sReN[0];
#pragma unroll
  for (int k = 0; k < 4; ++k) {
    const int n = k * 512 + tid;
    const int aa = s_as[n];
    const float num = (aa == n)
        ? (SAME ? atomicAdd(diagD + n, 0.f) : diagD[n])
        : Dens[(size_t)n * 2048 + aa];
    float denom = SAME ? atomicAdd(S + n, 0.f) : S[n];
    for (int t = 0; t < reN; ++t) denom -= Dens[(size_t)n * 2048 + s_re[t]];
    lambOut[n] = num / denom;
  }
}

// ------------------------------- GEMM --------------------------------------
// C[2048, *] = A[2048,2048] * Bcat^T, 128x128 tiles, 8 waves = 2m x 2n x 2k,
// BK=64, XOR-swizzled LDS (swizzle on global source address).
template <bool IS_L0>
__global__ __launch_bounds__(512, 4) void gemm_fused(
    const bf16* __restrict__ A, float* __restrict__ Dens,
    bf16* __restrict__ Hb, float* __restrict__ Fo,
    const float* __restrict__ bias, const float* __restrict__ SENin,
    const float* __restrict__ ninv_p, float* __restrict__ S,
    int* __restrict__ e, float* __restrict__ SENhOut,
    float* __restrict__ colsumH, float* __restrict__ diagD,
    int* __restrict__ cnt, int nblocks, float* __restrict__ lambOut,
    // L1-only (concurrent layer-0 tail):
    int* __restrict__ flagN, const float* __restrict__ SENh_r,
    const float* __restrict__ colsumH_r, int* __restrict__ e0,
    float* __restrict__ S0, float* __restrict__ diag0,
    float* __restrict__ Dens0, float* __restrict__ lamb0) {
  __shared__ __align__(16) char smem[32768];
  __shared__ int s_last;
  const int tid = threadIdx.x;

  // ---------------- L1 tail-0 block: stau1 + decide0 + lamb0 ---------------
  if (!IS_L0 && blockIdx.x == 24) {
    if (blockIdx.y != 0) return;
    float* r1 = (float*)(smem + 20480);
    float* r2 = (float*)(smem + 22528);
    float ssen = 0.f, sg2 = 0.f;
    for (int i = tid; i < 2048; i += 512) ssen += SENh_r[i];
    for (int c = tid; c < 2048; c += 512) {
      const float gm = colsumH_r[c] * (1.f / 2048.f);
      sg2 += gm * gm;
    }
    r1[tid] = ssen; r2[tid] = sg2;
    __syncthreads();
    for (int s = 256; s; s >>= 1) {
      if (tid < s) { r1[tid] += r1[tid + s]; r2[tid] += r2[tid + s]; }
      __syncthreads();
    }
    if (tid == 0) {
      const float stau = 0.5f * (r1[0] * (1.f / 2048.f) - r2[0]);
      atomicExch(flagN, __float_as_int(-1.f / stau));  // value IS ninv1
    }
    __syncthreads();
    run_decide_lamb<false>(smem, e0, Dens0, S0, diag0, lamb0);
    return;
  }

  const int wave = tid >> 6, lane = tid & 63;
  const int quad = lane >> 4, l16 = lane & 15;
  const int kg = wave & 1, wm = (wave >> 1) & 1, wn = (wave >> 2) & 1;
  const int m0 = blockIdx.y * 128, n0 = blockIdx.x * 128;
  const int waveM = wm * 64, waveN = wn * 64;
  const bool isGram = (n0 < 2048);
  const int sr8 = lane >> 3, slot = lane & 7;
  const int gk = (slot ^ sr8) * 8;  // swizzled global k-element offset
  const bf16* aSrc = A + (size_t)(m0 + wave * 16 + sr8) * 2048 + gk;
  const bf16* bSrc = A + (size_t)(n0 + wave * 16 + sr8) * 2048 + gk;
  char* const aDst = smem + wave * 2048;
  char* const bDst = smem + 16384 + wave * 2048;
  const int swz = ((kg * 4 + quad) ^ (l16 & 7)) * 16;
  const int aOff = (waveM + l16) * 128 + swz;
  const int bOff = 16384 + (waveN + l16) * 128 + swz;

  f32x4 acc[4][4] = {};
  for (int k0 = 0; k0 < 2048; k0 += 64) {
    gload16(aSrc + k0, (bf16*)aDst);
    gload16(aSrc + 8 * 2048 + k0, (bf16*)(aDst + 1024));
    gload16(bSrc + k0, (bf16*)bDst);
    gload16(bSrc + 8 * 2048 + k0, (bf16*)(bDst + 1024));
    __syncthreads();
    bf16x8 af[4], bfr[4];
#pragma unroll
    for (int i = 0; i < 4; ++i) af[i] = *(const bf16x8*)(smem + aOff + i * 2048);
#pragma unroll
    for (int j = 0; j < 4; ++j) bfr[j] = *(const bf16x8*)(smem + bOff + j * 2048);
#pragma unroll
    for (int i = 0; i < 4; ++i)
#pragma unroll
      for (int j = 0; j < 4; ++j)
        acc[i][j] = __builtin_amdgcn_mfma_f32_16x16x32_bf16(af[i], bfr[j], acc[i][j], 0, 0, 0);
    __syncthreads();
  }

  // ninv: L0 = plain read (prev dispatch); L1 = spin on flag (value = ninv1,
  // published ~3us into this dispatch -- epilogue is ~40us in, so 0 spins).
  float ninv = 0.f;
  if (isGram) {
    if (IS_L0) ninv = ninv_p[0];
    else {
      int fi;
      while ((fi = atomicOr(flagN, 0)) == 0) {}
      ninv = __int_as_float(fi);
    }
  }

  // epilogue: merge kg=1 partials into kg=0 via LDS (2 rounds of 2 i's)
  float colp[4] = {0.f, 0.f, 0.f, 0.f};
  char* const ex = smem + (wn * 2 + wm) * 8192;
#pragma unroll
  for (int round = 0; round < 2; ++round) {
    __syncthreads();
    if (kg == 1) {
#pragma unroll
      for (int ii = 0; ii < 2; ++ii)
#pragma unroll
        for (int j = 0; j < 4; ++j)
          *(f32x4*)(ex + (ii * 4 + j) * 1024 + lane * 16) = acc[round * 2 + ii][j];
    }
    __syncthreads();
    if (kg == 0) {
#pragma unroll
      for (int ii = 0; ii < 2; ++ii) {
        const int i = round * 2 + ii;
        const int rbase = m0 + waveM + i * 16 + quad * 4;
        if (isGram) {
          const f32x4 si4 = *(const f32x4*)(SENin + rbase);
          float rp[4] = {0.f, 0.f, 0.f, 0.f};
          int er = 0;
#pragma unroll
          for (int j = 0; j < 4; ++j) {
            f32x4 v = acc[i][j] + *(const f32x4*)(ex + (ii * 4 + j) * 1024 + lane * 16);
            const int col = n0 + waveN + j * 16 + l16;
            const float sj = SENin[col];
#pragma unroll
            for (int r = 0; r < 4; ++r) {
              const float dens = __expf((si4[r] + sj - 2.0f * v[r]) * ninv);
              Dens[(size_t)(rbase + r) * 2048 + col] = dens;
              rp[r] += dens;
              if (col < rbase + r && dens >= DELTA_F) er |= (1 << r);
              if (col == rbase + r) atomicExch(diagD + col, dens);
            }
          }
#pragma unroll
          for (int r = 0; r < 4; ++r) {
            float rv = rp[r];
            rv += __shfl_xor(rv, 1, 64); rv += __shfl_xor(rv, 2, 64);
            rv += __shfl_xor(rv, 4, 64); rv += __shfl_xor(rv, 8, 64);
            if (l16 == 0) atomicAdd(S + rbase + r, rv);
          }
          er |= __shfl_xor(er, 1, 64); er |= __shfl_xor(er, 2, 64);
          er |= __shfl_xor(er, 4, 64); er |= __shfl_xor(er, 8, 64);
          if (l16 == 0 && er) {
#pragma unroll
            for (int r = 0; r < 4; ++r)
              if ((er >> r) & 1) atomicOr(e + rbase + r, 1);
          }
        } else {
          float rn[4] = {0.f, 0.f, 0.f, 0.f};
#pragma unroll
          for (int j = 0; j < 4; ++j) {
            f32x4 v = acc[i][j] + *(const f32x4*)(ex + (ii * 4 + j) * 1024 + lane * 16);
            const int c2 = n0 - 2048 + waveN + j * 16 + l16;
            const float bv = bias[c2];
#pragma unroll
            for (int r = 0; r < 4; ++r) {
              const float hv = 1.0f / (1.0f + __expf(-(v[r] + bv)));
              if (IS_L0) {
                Hb[(size_t)(rbase + r) * 2048 + c2] = (bf16)hv;
                rn[r] += hv * hv;
                colp[j] += hv;
              } else {
                Fo[(size_t)(rbase + r) * 1024 + c2] = hv;
              }
            }
          }
          if (IS_L0) {
#pragma unroll
            for (int r = 0; r < 4; ++r) {
              float rv = rn[r];
              rv += __shfl_xor(rv, 1, 64); rv += __shfl_xor(rv, 2, 64);
              rv += __shfl_xor(rv, 4, 64); rv += __shfl_xor(rv, 8, 64);
              if (l16 == 0) atomicAdd(SENhOut + rbase + r, rv);
            }
          }
        }
      }
    }
  }
  if (IS_L0 && !isGram && kg == 0) {
#pragma unroll
    for (int j = 0; j < 4; ++j) {
      float cv = colp[j];
      cv += __shfl_xor(cv, 16, 64);
      cv += __shfl_xor(cv, 32, 64);
      if (lane < 16) atomicAdd(colsumH + (n0 - 2048 + waveN + j * 16 + lane), cv);
    }
  }

  if (IS_L0) return;  // no tail in L0 (moved to L1's tail-0 block)

  // ---- L1 last gemm block: decide1 + lamb1 (fence-free done-counter) ----
  __syncthreads();
  if (tid == 0) s_last = (atomicAdd(cnt, 1) == nblocks - 1);
  __syncthreads();
  if (!s_last) return;
  run_decide_lamb<true>(smem, e, Dens, S, diagD, lambOut);
}

// --------------------------- small kernels ---------------------------------
// grid 640: b<256 x-rows (convert + SENx atomicExch + 16-bin atomic colsum);
// b<512 W0 convert; else W1 convert. Last block computes stau0 (fence-free).
__global__ void f2b_all(const float* __restrict__ x, const float* __restrict__ W0,
                        const float* __restrict__ W1, bf16* __restrict__ xb,
                        bf16* __restrict__ wb0, bf16* __restrict__ wb1,
                        float* __restrict__ SENx, float* __restrict__ bins,
                        int* __restrict__ cntF, float* __restrict__ scal) {
  const int b = blockIdx.x, tid = threadIdx.x;
  const int wave = tid >> 6, lane = tid & 63;
  __shared__ float ws[8][4];
  __shared__ float red1[256], red2[256];
  __shared__ int s_last;
  if (b < 256) {
    const int r0 = b * 8;
    f32x4 c0 = {0.f, 0.f, 0.f, 0.f}, c1 = {0.f, 0.f, 0.f, 0.f};
    for (int r = 0; r < 8; ++r) {
      const float* src = x + (size_t)(r0 + r) * 2048;
      bf16* dst = xb + (size_t)(r0 + r) * 2048;
      f32x4 v0 = *(const f32x4*)(src + tid * 4);
      f32x4 v1 = *(const f32x4*)(src + 1024 + tid * 4);
      bf16x4 o0, o1;
      o0.x = (bf16)v0.x; o0.y = (bf16)v0.y; o0.z = (bf16)v0.z; o0.w = (bf16)v0.w;
      o1.x = (bf16)v1.x; o1.y = (bf16)v1.y; o1.z = (bf16)v1.z; o1.w = (bf16)v1.w;
      *(bf16x4*)(dst + tid * 4) = o0;
      *(bf16x4*)(dst + 1024 + tid * 4) = o1;
      c0 += v0; c1 += v1;
      float rn = v0.x * v0.x + v0.y * v0.y + v0.z * v0.z + v0.w * v0.w +
                 v1.x * v1.x + v1.y * v1.y + v1.z * v1.z + v1.w * v1.w;
      rn = wave_reduce(rn);
      if (lane == 0) ws[r][wave] = rn;
    }
    __syncthreads();
    if (tid < 8)
      atomicExch(SENx + r0 + tid, ws[tid][0] + ws[tid][1] + ws[tid][2] + ws[tid][3]);
    float* bin = bins + (size_t)(b & 15) * 2048;
    atomicAdd(bin + tid * 4 + 0, c0.x); atomicAdd(bin + tid * 4 + 1, c0.y);
    atomicAdd(bin + tid * 4 + 2, c0.z); atomicAdd(bin + tid * 4 + 3, c0.w);
    atomicAdd(bin + 1024 + tid * 4 + 0, c1.x); atomicAdd(bin + 1024 + tid * 4 + 1, c1.y);
    atomicAdd(bin + 1024 + tid * 4 + 2, c1.z); atomicAdd(bin + 1024 + tid * 4 + 3, c1.w);
  } else if (b < 512) {
    const size_t base = (size_t)(b - 256) * 16384;
    for (int c = tid * 4; c < 16384; c += 1024) {
      f32x4 v = *(const f32x4*)(W0 + base + c);
      bf16x4 o;
      o.x = (bf16)v.x; o.y = (bf16)v.y; o.z = (bf16)v.z; o.w = (bf16)v.w;
      *(bf16x4*)(wb0 + base + c) = o;
    }
  } else {
    const size_t base = (size_t)(b - 512) * 16384;
    for (int c = tid * 4; c < 16384; c += 1024) {
      f32x4 v = *(const f32x4*)(W1 + base + c);
      bf16x4 o;
      o.x = (bf16)v.x; o.y = (bf16)v.y; o.z = (bf16)v.z; o.w = (bf16)v.w;
      *(bf16x4*)(wb1 + base + c) = o;
    }
  }

  // fence-free done-counter finisher: stau0
  __syncthreads();
  if (tid == 0) s_last = (atomicAdd(cntF, 1) == 639);
  __syncthreads();
  if (!s_last) return;
  float ssen = 0.f;
  for (int i = tid; i < 2048; i += 256) ssen += atomicAdd(SENx + i, 0.f);
  float sg2 = 0.f;
  for (int c = tid; c < 2048; c += 256) {
    float cs = 0.f;
#pragma unroll
    for (int p = 0; p < 16; ++p) cs += atomicAdd(bins + (size_t)p * 2048 + c, 0.f);
    const float gm = cs * (1.f / 2048.f);
    sg2 += gm * gm;
  }
  red1[tid] = ssen; red2[tid] = sg2;
  __syncthreads();
  for (int s = 128; s; s >>= 1) {
    if (tid < s) { red1[tid] += red1[tid + s]; red2[tid] += red2[tid + s]; }
    __syncthreads();
  }
  if (tid == 0) {
    const float stau = 0.5f * (red1[0] * (1.f / 2048.f) - red2[0]);
    scal[0] = stau;
    scal[1] = -1.f / stau;
  }
}

// ------------------------------- driver ------------------------------------
extern "C" void kernel_launch(void* const* d_in, const int* in_sizes, int n_in,
                              void* d_out, int out_size, void* d_ws, size_t ws_size,
                              hipStream_t stream) {
  const float* x = (const float*)d_in[0];
  const float* W0 = (const float*)d_in[1];
  const float* b0 = (const float*)d_in[2];
  const float* W1 = (const float*)d_in[3];
  const float* b1 = (const float*)d_in[4];
  float* out = (float*)d_out;

  char* w = (char*)d_ws;
  bf16* xb = (bf16*)(w);                    // 8 MB  [L0 rows 0..2047]
  bf16* wb0 = (bf16*)(w + 8 * MBYTE);       // 8 MB  [L0 rows 2048..4095]
  bf16* hb = (bf16*)(w + 16 * MBYTE);       // 8 MB  [L1 rows 0..2047]
  bf16* wb1 = (bf16*)(w + 24 * MBYTE);      // 4 MB  [L1 rows 2048..3071]
  float* Dens0 = (float*)(w + 28 * MBYTE);  // 16 MB (L0 densities)
  float* Dens1 = (float*)(w);               // 16 MB (L1; overwrites dead xb+wb0)
  float* SENx = (float*)(w + 44 * MBYTE);   // 2048 (atomicExch; no zero needed)
  float* scal = SENx + 2048;                // 16: [0,1]=stau0,-1/stau0
  // ---- zeroed accumulator region (one memset node) ----
  float* zre = scal + 16;
  float* bins = zre;                        // 16*2048 colsum bins
  float* SENh = bins + 16 * 2048;           // 2048
  float* colsumH = SENh + 2048;             // 2048
  float* S0 = colsumH + 2048;               // 2048
  float* S1 = S0 + 2048;                    // 2048
  float* diagD0 = S1 + 2048;                // 2048
  float* diagD1 = diagD0 + 2048;            // 2048
  int* e0 = (int*)(diagD1 + 2048);          // 2048
  int* e1 = e0 + 2048;                      // 2048
  int* cntF = e1 + 2048;
  int* cnt1 = cntF + 1;
  int* flagN = cnt1 + 1;                    // ready flag; value = ninv1
  const size_t zwords = 16 * 2048 + 8 * 2048 + 16;

  float* lamb0 = out + (size_t)2048 * 1024;
  float* lamb1 = lamb0 + 2048;

  hipMemsetAsync(zre, 0, zwords * 4, stream);
  f2b_all<<<640, 256, 0, stream>>>(x, W0, W1, xb, wb0, wb1, SENx, bins, cntF, scal);
  gemm_fused<true><<<dim3(32, 16), 512, 0, stream>>>(
      xb, Dens0, hb, nullptr, b0, SENx, scal + 1, S0, e0, SENh, colsumH,
      diagD0, nullptr, 0, nullptr,
      nullptr, nullptr, nullptr, nullptr, nullptr, nullptr, nullptr, nullptr);
  gemm_fused<false><<<dim3(25, 16), 512, 0, stream>>>(
      hb, Dens1, nullptr, out, b1, SENh, nullptr, S1, e1, nullptr, nullptr,
      diagD1, cnt1, 384, lamb1,
      flagN, SENh, colsumH, e0, S0, diagD0, Dens0, lamb0);
}